// Round 5
// baseline (158.284 us; speedup 1.0000x reference)
//
#include <hip/hip_runtime.h>

#define BB 16384
#define DD 256
#define EE 8
#define HH 128
#define MAGIC 0x13579BDF

typedef __attribute__((ext_vector_type(8))) short short8;   // 8 bf16 = 4 VGPRs
typedef __attribute__((ext_vector_type(4))) float f32x4;

// fp32 -> bf16 round-to-nearest-even (values are finite; no NaN care needed)
__device__ __forceinline__ ushort f2bf(float f){
    const unsigned u = __float_as_uint(f);
    return (ushort)((u + 0x7fffu + ((u >> 16) & 1u)) >> 16);
}
__device__ __forceinline__ float bf2f(ushort s){
    return __uint_as_float(((unsigned)s) << 16);
}
__device__ __forceinline__ float fast_tanh(float v){
    v = fminf(fmaxf(v, -15.0f), 15.0f);
    const float a = __expf(2.0f * v);
    return (a - 1.0f) / (a + 1.0f);
}

// ---------------------------------------------------------------------------
// Merged prep: blocks 0..95 transpose W1/Wp -> bf16 [e][h][k]; blocks 96..1119
// route 16 rows each (block-aggregated atomics, zero their out[] rows).
// counts-zero ordering: block 0 zeroes counts then release-stores MAGIC flag;
// router blocks acquire-spin on the flag only right before their 8 global
// atomicAdds (all local work done first, so the spin is ~0 in practice).
// No-deadlock: 1120 blocks x ~26KB LDS -> 6 blocks/CU x 256 CU = 1536 slots,
// all blocks resident regardless of dispatch order. Flag starts != MAGIC under
// any init (0xAA poison, zeros, or garbage at 2^-32).
__global__ __launch_bounds__(256) void prep_kernel(
    const float* __restrict__ W1, const float* __restrict__ Wp,
    ushort* __restrict__ W1t, ushort* __restrict__ Wpt,
    const float* __restrict__ x, const float* __restrict__ Wg,
    int* __restrict__ counts, int* __restrict__ flag,
    int* __restrict__ rowids, float* __restrict__ wgts, float* __restrict__ out)
{
    __shared__ float tile[64 * 68];            // transpose: 17.4 KB
    __shared__ __align__(16) float WgT[EE][DD];  // routing: 8 KB
    __shared__ int   le[32];
    __shared__ float lw[32];
    __shared__ int   loff[32];
    __shared__ int   lcount[EE];
    __shared__ int   lbase[EE];

    const int t = threadIdx.x;

    if (blockIdx.x < 96){
        // ---------------- transpose path ----------------
        int b = blockIdx.x;
        if (b == 0){
            if (t < EE) atomicExch(&counts[t], 0);
            __syncthreads();
            if (t == 0){
                __threadfence();
                __hip_atomic_store(flag, MAGIC, __ATOMIC_RELEASE, __HIP_MEMORY_SCOPE_AGENT);
            }
        }
        const float* src; ushort* dst; int K;
        int k0, h0;
        if (b < 64){                                    // W1: 8e x 4kt x 2ht
            const int e = b >> 3, kt = (b >> 1) & 3, ht = b & 1;
            src = W1 + (size_t)e * DD * HH;  dst = W1t + (size_t)e * HH * DD;
            K = DD; k0 = kt * 64; h0 = ht * 64;
        } else {                                        // Wp: 8e x 2kt x 2ht
            b -= 64;
            const int e = b >> 2, kt = (b >> 1) & 1, ht = b & 1;
            src = Wp + (size_t)e * HH * HH;  dst = Wpt + (size_t)e * HH * HH;
            K = HH; k0 = kt * 64; h0 = ht * 64;
        }
        #pragma unroll
        for (int j = 0; j < 4; j++){
            const int idx = t + 256 * j;               // 1024 float4 = 64x64
            const int kk = idx >> 4, hh = (idx & 15) * 4;
            const float4 v = *(const float4*)(src + (size_t)(k0 + kk) * HH + h0 + hh);
            *(float4*)&tile[kk * 68 + hh] = v;
        }
        __syncthreads();
        #pragma unroll
        for (int j = 0; j < 4; j++){
            const int idx = t + 256 * j;
            const int hh = idx >> 4, kk = (idx & 15) * 4;
            ushort4 o;
            o.x = f2bf(tile[(kk + 0) * 68 + hh]);
            o.y = f2bf(tile[(kk + 1) * 68 + hh]);
            o.z = f2bf(tile[(kk + 2) * 68 + hh]);
            o.w = f2bf(tile[(kk + 3) * 68 + hh]);
            *(ushort4*)&dst[(size_t)(h0 + hh) * K + k0 + kk] = o;
        }
        return;
    }

    // ---------------- routing path: 16 rows/block ----------------
    const int rb = blockIdx.x - 96;
    const int rowBase = rb * 16;
    if (t < 16) out[rowBase + t] = 0.0f;
    {
        const float4* g = (const float4*)(Wg + t * EE);
        const float4 a = g[0], b2 = g[1];
        WgT[0][t] = a.x;  WgT[1][t] = a.y;  WgT[2][t] = a.z;  WgT[3][t] = a.w;
        WgT[4][t] = b2.x; WgT[5][t] = b2.y; WgT[6][t] = b2.z; WgT[7][t] = b2.w;
    }
    if (t < EE) lcount[t] = 0;
    __syncthreads();

    const int lane = t & 63;
    const int wid  = t >> 6;

    for (int it = 0; it < 4; it++){
        const int slot = wid * 4 + it;
        const int row  = rowBase + slot;
        const float4 xv = *(const float4*)(x + row * DD + lane * 4);
        float p[EE];
        #pragma unroll
        for (int e = 0; e < EE; e++){
            const float4 w = *(const float4*)&WgT[e][lane * 4];
            p[e] = xv.x * w.x + xv.y * w.y + xv.z * w.z + xv.w * w.w;
        }
        #pragma unroll
        for (int off = 32; off >= 1; off >>= 1){
            #pragma unroll
            for (int e = 0; e < EE; e++) p[e] += __shfl_down(p[e], off, 64);
        }
        if (lane == 0){
            int e0 = 0; float l0 = p[0];
            #pragma unroll
            for (int e = 1; e < EE; e++){ if (p[e] > l0){ l0 = p[e]; e0 = e; } }
            int e1 = -1; float l1 = -3.0e38f;
            #pragma unroll
            for (int e = 0; e < EE; e++){ if (e != e0 && p[e] > l1){ l1 = p[e]; e1 = e; } }
            const float tt  = __expf(l1 - l0);            // <= 1
            const float inv = 1.0f / (1.0f + tt);
            le[slot]      = e0;  lw[slot]      = inv;
            le[16 + slot] = e1;  lw[16 + slot] = tt * inv;
        }
    }
    __syncthreads();
    if (t < 32) loff[t] = atomicAdd(&lcount[le[t]], 1);
    // wait until counts[] is known-zeroed (block 0), then claim global ranges
    if (t == 0){
        while (__hip_atomic_load(flag, __ATOMIC_ACQUIRE, __HIP_MEMORY_SCOPE_AGENT) != MAGIC)
            __builtin_amdgcn_s_sleep(1);
    }
    __syncthreads();
    if (t < EE) lbase[t] = atomicAdd(&counts[t], lcount[t]);
    __syncthreads();
    if (t < 32){
        const int e   = le[t];
        const int pos = lbase[e] + loff[t];
        rowids[e * BB + pos] = rowBase + (t & 15);
        wgts[e * BB + pos]   = lw[t];
    }
}

// ---------------------------------------------------------------------------
// Expert kernel, MFMA bf16 (unchanged from round 4). Block = 4 waves, 64 rows,
// 64x128 output tile; wave w: rows 32*(w>>1), cols 64*(w&1), 2x4 16x16 tiles.
// mfma_f32_16x16x32_bf16: A[m=lane&15][k=quad*8+j], B[k][n=lane&15],
// C col=lane&15 row=quad*4+reg.
#define XS_S 264   // 256 + 8 bf16 pad
#define CS_S 136   // 128 + 8 bf16 pad

__global__ __launch_bounds__(256, 2) void expert_kernel(
    const float* __restrict__ x,
    const ushort* __restrict__ W1t, const float* __restrict__ b1,
    const ushort* __restrict__ Wpt, const float* __restrict__ bp,
    const float* __restrict__ mix_logit,
    const float* __restrict__ Wo, const float* __restrict__ bo,
    const int* __restrict__ counts, const int* __restrict__ rowids,
    const float* __restrict__ wgts, float* __restrict__ out)
{
    const int me    = blockIdx.y;
    const int cnt   = counts[me];
    const int start = blockIdx.x * 64;
    if (start >= cnt) return;

    __shared__ ushort Xs[64 * XS_S];     // 33.8 KB
    __shared__ ushort coreS[64 * CS_S];  // 17.4 KB
    __shared__ int   rid_s[64];
    __shared__ float w_s[64];

    const int t = threadIdx.x;
    if (t < 64){
        const int idx = start + t;
        if (idx < cnt){ rid_s[t] = rowids[me * BB + idx]; w_s[t] = wgts[me * BB + idx]; }
        else          { rid_s[t] = 0;                     w_s[t] = 0.0f; }
    }
    __syncthreads();

    #pragma unroll
    for (int j = 0; j < 16; j++){
        const int idx = t + 256 * j;          // 4096 float4 = 64 x 256
        const int r  = idx >> 6;
        const int kq = (idx & 63) << 2;
        const float4 v = *(const float4*)(x + (size_t)rid_s[r] * DD + kq);
        ushort4 bv;
        bv.x = f2bf(v.x); bv.y = f2bf(v.y); bv.z = f2bf(v.z); bv.w = f2bf(v.w);
        *(ushort4*)&Xs[r * XS_S + kq] = bv;
    }
    __syncthreads();

    const int lane = t & 63;
    const int w    = t >> 6;
    const int m16  = lane & 15;
    const int q    = lane >> 4;
    const int r0   = 32 * (w >> 1);
    const int c0   = 64 * (w & 1);

    // ---- GEMM1: core_pre = X @ W1 + b1 ----
    f32x4 acc[2][4];
    #pragma unroll
    for (int ct = 0; ct < 4; ct++){
        const float bj = b1[me * HH + c0 + ct * 16 + m16];
        #pragma unroll
        for (int rt = 0; rt < 2; rt++) acc[rt][ct] = (f32x4){bj, bj, bj, bj};
    }
    const ushort* W1te = W1t + (size_t)me * HH * DD;
    #pragma unroll
    for (int ks = 0; ks < 8; ks++){
        const int k0 = ks * 32;
        short8 af[2], bf[4];
        #pragma unroll
        for (int rt = 0; rt < 2; rt++)
            af[rt] = *(const short8*)&Xs[(r0 + rt * 16 + m16) * XS_S + k0 + q * 8];
        #pragma unroll
        for (int ct = 0; ct < 4; ct++)
            bf[ct] = *(const short8*)&W1te[(size_t)(c0 + ct * 16 + m16) * DD + k0 + q * 8];
        #pragma unroll
        for (int rt = 0; rt < 2; rt++)
            #pragma unroll
            for (int ct = 0; ct < 4; ct++)
                acc[rt][ct] = __builtin_amdgcn_mfma_f32_16x16x32_bf16(af[rt], bf[ct], acc[rt][ct], 0, 0, 0);
    }

    // relu -> bf16 core into LDS (A-operand source for GEMM2 + epilogue reuse)
    #pragma unroll
    for (int rt = 0; rt < 2; rt++)
        #pragma unroll
        for (int ct = 0; ct < 4; ct++)
            #pragma unroll
            for (int j = 0; j < 4; j++){
                const int row = r0 + rt * 16 + q * 4 + j;
                const int col = c0 + ct * 16 + m16;
                coreS[row * CS_S + col] = f2bf(fmaxf(acc[rt][ct][j], 0.0f));
            }
    __syncthreads();

    // ---- GEMM2: plast_pre = core @ Wp + bp ----
    #pragma unroll
    for (int ct = 0; ct < 4; ct++){
        const float bj = bp[me * HH + c0 + ct * 16 + m16];
        #pragma unroll
        for (int rt = 0; rt < 2; rt++) acc[rt][ct] = (f32x4){bj, bj, bj, bj};
    }
    const ushort* Wpte = Wpt + (size_t)me * HH * HH;
    #pragma unroll
    for (int ks = 0; ks < 4; ks++){
        const int k0 = ks * 32;
        short8 af[2], bf[4];
        #pragma unroll
        for (int rt = 0; rt < 2; rt++)
            af[rt] = *(const short8*)&coreS[(r0 + rt * 16 + m16) * CS_S + k0 + q * 8];
        #pragma unroll
        for (int ct = 0; ct < 4; ct++)
            bf[ct] = *(const short8*)&Wpte[(size_t)(c0 + ct * 16 + m16) * HH + k0 + q * 8];
        #pragma unroll
        for (int rt = 0; rt < 2; rt++)
            #pragma unroll
            for (int ct = 0; ct < 4; ct++)
                acc[rt][ct] = __builtin_amdgcn_mfma_f32_16x16x32_bf16(af[rt], bf[ct], acc[rt][ct], 0, 0, 0);
    }

    // ---- epilogue: out_row = sum_h [core*(1-m) + m*tanh(plast)] * Wo + bo ----
    const float mv  = 1.0f / (1.0f + __expf(-mix_logit[me]));
    const float om  = 1.0f - mv;
    const float bov = bo[me];
    float wo[4];
    #pragma unroll
    for (int ct = 0; ct < 4; ct++) wo[ct] = Wo[me * HH + c0 + ct * 16 + m16];

    float red[2][4];
    #pragma unroll
    for (int rt = 0; rt < 2; rt++)
        #pragma unroll
        for (int j = 0; j < 4; j++){
            float s = 0.0f;
            const int row = r0 + rt * 16 + q * 4 + j;
            #pragma unroll
            for (int ct = 0; ct < 4; ct++){
                const int col = c0 + ct * 16 + m16;
                const float pl = fast_tanh(acc[rt][ct][j]);
                const float cv = bf2f(coreS[row * CS_S + col]);
                s = fmaf(om * cv + mv * pl, wo[ct], s);
            }
            red[rt][j] = s;
        }
    #pragma unroll
    for (int off = 8; off >= 1; off >>= 1)
        #pragma unroll
        for (int rt = 0; rt < 2; rt++)
            #pragma unroll
            for (int j = 0; j < 4; j++)
                red[rt][j] += __shfl_xor(red[rt][j], off, 64);   // reduce over m16

    if (m16 == 0){
        const float bb = (c0 == 0) ? bov : 0.0f;   // bias from one col-half only
        #pragma unroll
        for (int rt = 0; rt < 2; rt++)
            #pragma unroll
            for (int j = 0; j < 4; j++){
                const int row = r0 + rt * 16 + q * 4 + j;
                const float ww = w_s[row];
                if (ww != 0.0f) atomicAdd(&out[rid_s[row]], (red[rt][j] + bb) * ww);
            }
    }
}

extern "C" void kernel_launch(void* const* d_in, const int* in_sizes, int n_in,
                              void* d_out, int out_size, void* d_ws, size_t ws_size,
                              hipStream_t stream) {
    (void)in_sizes; (void)n_in; (void)out_size; (void)ws_size;
    const float* x   = (const float*)d_in[0];
    const float* Wg  = (const float*)d_in[1];
    const float* W1  = (const float*)d_in[2];
    const float* b1  = (const float*)d_in[3];
    const float* Wp  = (const float*)d_in[4];
    const float* bp  = (const float*)d_in[5];
    const float* ml  = (const float*)d_in[6];
    const float* Wo  = (const float*)d_in[7];
    const float* bo  = (const float*)d_in[8];
    float* out = (float*)d_out;

    // ws layout (16B-aligned blocks):
    //   counts 8 ints + flag at int[16] (256B block) | rowids E*B*4 | wgts E*B*4
    //   | W1t E*H*D*2 | Wpt E*H*H*2
    char* ws = (char*)d_ws;
    int*    counts = (int*)ws;
    int*    flag   = (int*)(ws + 64);
    int*    rowids = (int*)(ws + 256);
    float*  wgts   = (float*)(ws + 256 + (size_t)EE * BB * 4);
    ushort* W1t    = (ushort*)(ws + 256 + 2 * (size_t)EE * BB * 4);
    ushort* Wpt    = W1t + (size_t)EE * HH * DD;

    // 2 dispatches: prep (transpose + routing + counts/out zeroing), expert.
    prep_kernel<<<96 + BB / 16, 256, 0, stream>>>(
        W1, Wp, W1t, Wpt, x, Wg, counts, flag, rowids, wgts, out);
    expert_kernel<<<dim3(BB / 64, EE), 256, 0, stream>>>(
        x, W1t, b1, Wpt, bp, ml, Wo, bo, counts, rowids, wgts, out);
}

// Round 6
// 119.645 us; speedup vs baseline: 1.3229x; 1.3229x over previous
//
#include <hip/hip_runtime.h>

#define BB 16384
#define DD 256
#define EE 8
#define HH 128
// counts are spread one-per-256B so a wave's 8 expert atomics hit 8 different
// L2 cachelines (parallel TCC channels) instead of serializing on one line.
#define CSTRIDE 64

typedef __attribute__((ext_vector_type(8))) short short8;   // 8 bf16 = 4 VGPRs
typedef __attribute__((ext_vector_type(4))) float f32x4;

// fp32 -> bf16 round-to-nearest-even (values are finite; no NaN care needed)
__device__ __forceinline__ ushort f2bf(float f){
    const unsigned u = __float_as_uint(f);
    return (ushort)((u + 0x7fffu + ((u >> 16) & 1u)) >> 16);
}
__device__ __forceinline__ float bf2f(ushort s){
    return __uint_as_float(((unsigned)s) << 16);
}
__device__ __forceinline__ float fast_tanh(float v){
    v = fminf(fmaxf(v, -15.0f), 15.0f);
    const float a = __expf(2.0f * v);
    return (a - 1.0f) / (a + 1.0f);
}

// ---------------------------------------------------------------------------
// Prepass: W1 [e][k=256][h=128] fp32 -> W1t [e][h][k] bf16; Wp likewise.
// Block 0 zeroes the routing counts -- stream-ordered before routing (kernel
// boundary is a device-wide barrier), replacing a hipMemsetAsync dispatch.
__global__ __launch_bounds__(256) void transpose_kernel(
    const float* __restrict__ W1, const float* __restrict__ Wp,
    ushort* __restrict__ W1t, ushort* __restrict__ Wpt, int* __restrict__ counts)
{
    __shared__ float tile[64 * 68];   // 64x64 fp32 tile, pad 68 vs bank conflicts
    int b = blockIdx.x;
    const int t = threadIdx.x;
    if (b == 0 && t < EE) counts[t * CSTRIDE] = 0;
    const float* src; ushort* dst; int K;
    int k0, h0;
    if (b < 64){                                    // W1: 8e x 4kt x 2ht
        const int e = b >> 3, kt = (b >> 1) & 3, ht = b & 1;
        src = W1 + (size_t)e * DD * HH;  dst = W1t + (size_t)e * HH * DD;
        K = DD; k0 = kt * 64; h0 = ht * 64;
    } else {                                        // Wp: 8e x 2kt x 2ht
        b -= 64;
        const int e = b >> 2, kt = (b >> 1) & 1, ht = b & 1;
        src = Wp + (size_t)e * HH * HH;  dst = Wpt + (size_t)e * HH * HH;
        K = HH; k0 = kt * 64; h0 = ht * 64;
    }
    #pragma unroll
    for (int j = 0; j < 4; j++){
        const int idx = t + 256 * j;               // 1024 float4 = 64x64
        const int kk = idx >> 4, hh = (idx & 15) * 4;
        const float4 v = *(const float4*)(src + (size_t)(k0 + kk) * HH + h0 + hh);
        *(float4*)&tile[kk * 68 + hh] = v;
    }
    __syncthreads();
    #pragma unroll
    for (int j = 0; j < 4; j++){
        const int idx = t + 256 * j;
        const int hh = idx >> 4, kk = (idx & 15) * 4;
        ushort4 o;
        o.x = f2bf(tile[(kk + 0) * 68 + hh]);
        o.y = f2bf(tile[(kk + 1) * 68 + hh]);
        o.z = f2bf(tile[(kk + 2) * 68 + hh]);
        o.w = f2bf(tile[(kk + 3) * 68 + hh]);
        *(ushort4*)&dst[(size_t)(h0 + hh) * K + k0 + kk] = o;
    }
}

// ---------------------------------------------------------------------------
// Routing: 32 rows/block (512 blocks -> 2 blocks/CU). Block-aggregated global
// atomics on line-spread counters. Also zeroes this block's out[] rows
// (stream-ordered before the expert kernel). Stays fp32: bf16 logits would
// flip near-tie top-2 picks.
__global__ __launch_bounds__(256) void routing_kernel(
    const float* __restrict__ x, const float* __restrict__ Wg,
    int* __restrict__ counts, int* __restrict__ rowids, float* __restrict__ wgts,
    float* __restrict__ out)
{
    __shared__ __align__(16) float WgT[EE][DD];
    __shared__ int   le[64];      // slot s: e0 at [s], e1 at [32+s]
    __shared__ float lw[64];
    __shared__ int   loff[64];
    __shared__ int   lcount[EE];
    __shared__ int   lbase[EE];

    const int t = threadIdx.x;
    const int rowBase = blockIdx.x * 32;
    if (t < 32) out[rowBase + t] = 0.0f;
    {
        const float4* g = (const float4*)(Wg + t * EE);
        const float4 a = g[0], b = g[1];
        WgT[0][t] = a.x; WgT[1][t] = a.y; WgT[2][t] = a.z; WgT[3][t] = a.w;
        WgT[4][t] = b.x; WgT[5][t] = b.y; WgT[6][t] = b.z; WgT[7][t] = b.w;
    }
    if (t < EE) lcount[t] = 0;
    __syncthreads();

    const int lane = t & 63;
    const int wid  = t >> 6;

    for (int it = 0; it < 8; it++){
        const int slot = wid * 8 + it;
        const int row  = rowBase + slot;
        const float4 xv = *(const float4*)(x + row * DD + lane * 4);
        float p[EE];
        #pragma unroll
        for (int e = 0; e < EE; e++){
            const float4 w = *(const float4*)&WgT[e][lane * 4];
            p[e] = xv.x * w.x + xv.y * w.y + xv.z * w.z + xv.w * w.w;
        }
        #pragma unroll
        for (int off = 32; off >= 1; off >>= 1){
            #pragma unroll
            for (int e = 0; e < EE; e++) p[e] += __shfl_down(p[e], off, 64);
        }
        if (lane == 0){
            int e0 = 0; float l0 = p[0];
            #pragma unroll
            for (int e = 1; e < EE; e++){ if (p[e] > l0){ l0 = p[e]; e0 = e; } }
            int e1 = -1; float l1 = -3.0e38f;
            #pragma unroll
            for (int e = 0; e < EE; e++){ if (e != e0 && p[e] > l1){ l1 = p[e]; e1 = e; } }
            const float tt  = __expf(l1 - l0);            // <= 1
            const float inv = 1.0f / (1.0f + tt);
            le[slot]      = e0;  lw[slot]      = inv;
            le[32 + slot] = e1;  lw[32 + slot] = tt * inv;
        }
    }
    __syncthreads();
    if (t < 64) loff[t] = atomicAdd(&lcount[le[t]], 1);
    __syncthreads();
    if (t < EE) lbase[t] = atomicAdd(&counts[t * CSTRIDE], lcount[t]);
    __syncthreads();
    if (t < 64){
        const int e   = le[t];
        const int pos = lbase[e] + loff[t];
        rowids[e * BB + pos] = rowBase + (t & 31);
        wgts[e * BB + pos]   = lw[t];
    }
}

// ---------------------------------------------------------------------------
// Expert kernel, MFMA bf16 (structure unchanged since round 3). Block = 4
// waves, 64 gathered rows, 64x128 output tile; wave w: rows 32*(w>>1), cols
// 64*(w&1), 2x4 16x16 tiles. mfma_f32_16x16x32_bf16: A[m=lane&15][k=quad*8+j],
// B[k][n=lane&15], C col=lane&15 row=quad*4+reg.
#define XS_S 264   // 256 + 8 bf16 pad
#define CS_S 136   // 128 + 8 bf16 pad

__global__ __launch_bounds__(256, 2) void expert_kernel(
    const float* __restrict__ x,
    const ushort* __restrict__ W1t, const float* __restrict__ b1,
    const ushort* __restrict__ Wpt, const float* __restrict__ bp,
    const float* __restrict__ mix_logit,
    const float* __restrict__ Wo, const float* __restrict__ bo,
    const int* __restrict__ counts, const int* __restrict__ rowids,
    const float* __restrict__ wgts, float* __restrict__ out)
{
    const int me    = blockIdx.y;
    const int cnt   = counts[me * CSTRIDE];
    const int start = blockIdx.x * 64;
    if (start >= cnt) return;

    __shared__ ushort Xs[64 * XS_S];     // 33.8 KB
    __shared__ ushort coreS[64 * CS_S];  // 17.4 KB
    __shared__ int   rid_s[64];
    __shared__ float w_s[64];

    const int t = threadIdx.x;
    if (t < 64){
        const int idx = start + t;
        if (idx < cnt){ rid_s[t] = rowids[me * BB + idx]; w_s[t] = wgts[me * BB + idx]; }
        else          { rid_s[t] = 0;                     w_s[t] = 0.0f; }
    }
    __syncthreads();

    #pragma unroll
    for (int j = 0; j < 16; j++){
        const int idx = t + 256 * j;          // 4096 float4 = 64 x 256
        const int r  = idx >> 6;
        const int kq = (idx & 63) << 2;
        const float4 v = *(const float4*)(x + (size_t)rid_s[r] * DD + kq);
        ushort4 bv;
        bv.x = f2bf(v.x); bv.y = f2bf(v.y); bv.z = f2bf(v.z); bv.w = f2bf(v.w);
        *(ushort4*)&Xs[r * XS_S + kq] = bv;
    }
    __syncthreads();

    const int lane = t & 63;
    const int w    = t >> 6;
    const int m16  = lane & 15;
    const int q    = lane >> 4;
    const int r0   = 32 * (w >> 1);
    const int c0   = 64 * (w & 1);

    // ---- GEMM1: core_pre = X @ W1 + b1 ----
    f32x4 acc[2][4];
    #pragma unroll
    for (int ct = 0; ct < 4; ct++){
        const float bj = b1[me * HH + c0 + ct * 16 + m16];
        #pragma unroll
        for (int rt = 0; rt < 2; rt++) acc[rt][ct] = (f32x4){bj, bj, bj, bj};
    }
    const ushort* W1te = W1t + (size_t)me * HH * DD;
    #pragma unroll
    for (int ks = 0; ks < 8; ks++){
        const int k0 = ks * 32;
        short8 af[2], bf[4];
        #pragma unroll
        for (int rt = 0; rt < 2; rt++)
            af[rt] = *(const short8*)&Xs[(r0 + rt * 16 + m16) * XS_S + k0 + q * 8];
        #pragma unroll
        for (int ct = 0; ct < 4; ct++)
            bf[ct] = *(const short8*)&W1te[(size_t)(c0 + ct * 16 + m16) * DD + k0 + q * 8];
        #pragma unroll
        for (int rt = 0; rt < 2; rt++)
            #pragma unroll
            for (int ct = 0; ct < 4; ct++)
                acc[rt][ct] = __builtin_amdgcn_mfma_f32_16x16x32_bf16(af[rt], bf[ct], acc[rt][ct], 0, 0, 0);
    }

    // relu -> bf16 core into LDS (A-operand source for GEMM2 + epilogue reuse)
    #pragma unroll
    for (int rt = 0; rt < 2; rt++)
        #pragma unroll
        for (int ct = 0; ct < 4; ct++)
            #pragma unroll
            for (int j = 0; j < 4; j++){
                const int row = r0 + rt * 16 + q * 4 + j;
                const int col = c0 + ct * 16 + m16;
                coreS[row * CS_S + col] = f2bf(fmaxf(acc[rt][ct][j], 0.0f));
            }
    __syncthreads();

    // ---- GEMM2: plast_pre = core @ Wp + bp ----
    #pragma unroll
    for (int ct = 0; ct < 4; ct++){
        const float bj = bp[me * HH + c0 + ct * 16 + m16];
        #pragma unroll
        for (int rt = 0; rt < 2; rt++) acc[rt][ct] = (f32x4){bj, bj, bj, bj};
    }
    const ushort* Wpte = Wpt + (size_t)me * HH * HH;
    #pragma unroll
    for (int ks = 0; ks < 4; ks++){
        const int k0 = ks * 32;
        short8 af[2], bf[4];
        #pragma unroll
        for (int rt = 0; rt < 2; rt++)
            af[rt] = *(const short8*)&coreS[(r0 + rt * 16 + m16) * CS_S + k0 + q * 8];
        #pragma unroll
        for (int ct = 0; ct < 4; ct++)
            bf[ct] = *(const short8*)&Wpte[(size_t)(c0 + ct * 16 + m16) * HH + k0 + q * 8];
        #pragma unroll
        for (int rt = 0; rt < 2; rt++)
            #pragma unroll
            for (int ct = 0; ct < 4; ct++)
                acc[rt][ct] = __builtin_amdgcn_mfma_f32_16x16x32_bf16(af[rt], bf[ct], acc[rt][ct], 0, 0, 0);
    }

    // ---- epilogue: out_row = sum_h [core*(1-m) + m*tanh(plast)] * Wo + bo ----
    const float mv  = 1.0f / (1.0f + __expf(-mix_logit[me]));
    const float om  = 1.0f - mv;
    const float bov = bo[me];
    float wo[4];
    #pragma unroll
    for (int ct = 0; ct < 4; ct++) wo[ct] = Wo[me * HH + c0 + ct * 16 + m16];

    float red[2][4];
    #pragma unroll
    for (int rt = 0; rt < 2; rt++)
        #pragma unroll
        for (int j = 0; j < 4; j++){
            float s = 0.0f;
            const int row = r0 + rt * 16 + q * 4 + j;
            #pragma unroll
            for (int ct = 0; ct < 4; ct++){
                const int col = c0 + ct * 16 + m16;
                const float pl = fast_tanh(acc[rt][ct][j]);
                const float cv = bf2f(coreS[row * CS_S + col]);
                s = fmaf(om * cv + mv * pl, wo[ct], s);
            }
            red[rt][j] = s;
        }
    #pragma unroll
    for (int off = 8; off >= 1; off >>= 1)
        #pragma unroll
        for (int rt = 0; rt < 2; rt++)
            #pragma unroll
            for (int j = 0; j < 4; j++)
                red[rt][j] += __shfl_xor(red[rt][j], off, 64);   // reduce over m16

    if (m16 == 0){
        const float bb = (c0 == 0) ? bov : 0.0f;   // bias from one col-half only
        #pragma unroll
        for (int rt = 0; rt < 2; rt++)
            #pragma unroll
            for (int j = 0; j < 4; j++){
                const int row = r0 + rt * 16 + q * 4 + j;
                const float ww = w_s[row];
                if (ww != 0.0f) atomicAdd(&out[rid_s[row]], (red[rt][j] + bb) * ww);
            }
    }
}

extern "C" void kernel_launch(void* const* d_in, const int* in_sizes, int n_in,
                              void* d_out, int out_size, void* d_ws, size_t ws_size,
                              hipStream_t stream) {
    (void)in_sizes; (void)n_in; (void)out_size; (void)ws_size;
    const float* x   = (const float*)d_in[0];
    const float* Wg  = (const float*)d_in[1];
    const float* W1  = (const float*)d_in[2];
    const float* b1  = (const float*)d_in[3];
    const float* Wp  = (const float*)d_in[4];
    const float* bp  = (const float*)d_in[5];
    const float* ml  = (const float*)d_in[6];
    const float* Wo  = (const float*)d_in[7];
    const float* bo  = (const float*)d_in[8];
    float* out = (float*)d_out;

    // ws layout (16B-aligned blocks):
    //   counts: 8 counters spread at 256B stride (2KB total) | rowids E*B*4
    //   | wgts E*B*4 | W1t E*H*D*2 | Wpt E*H*H*2
    char* ws = (char*)d_ws;
    int*    counts = (int*)ws;
    int*    rowids = (int*)(ws + 2048);
    float*  wgts   = (float*)(ws + 2048 + (size_t)EE * BB * 4);
    ushort* W1t    = (ushort*)(ws + 2048 + 2 * (size_t)EE * BB * 4);
    ushort* Wpt    = W1t + (size_t)EE * HH * DD;

    // 3 dispatches, no memsets: transpose zeroes counts (block 0), routing
    // zeroes out[] (its own rows) -- both stream-ordered before their readers.
    // (Round-5's single-dispatch merge with an intra-kernel flag spin regressed
    // 119->158us; reverted.)
    transpose_kernel<<<96, 256, 0, stream>>>(W1, Wp, W1t, Wpt, counts);
    routing_kernel<<<BB / 32, 256, 0, stream>>>(x, Wg, counts, rowids, wgts, out);
    expert_kernel<<<dim3(BB / 64, EE), 256, 0, stream>>>(
        x, W1t, b1, Wpt, bp, ml, Wo, bo, counts, rowids, wgts, out);
}